// Round 3
// baseline (4892.753 us; speedup 1.0000x reference)
//
#include <hip/hip_runtime.h>

#define TT 512
#define BB 64
#define HH 1024
#define G4 4096

typedef _Float16 h8 __attribute__((ext_vector_type(8)));
typedef float f4 __attribute__((ext_vector_type(4)));
typedef unsigned long long u64;

// Raw workgroup barrier draining ONLY LDS ops (lgkmcnt). Global loads stay in
// flight across it (counted vmcnt waits are inserted by the compiler at the
// register use). sched_barrier(0) fences compiler motion across the asm.
#define BAR_LGKM() do {                                      \
  asm volatile("s_waitcnt lgkmcnt(0)" ::: "memory");         \
  __builtin_amdgcn_sched_barrier(0);                         \
  __builtin_amdgcn_s_barrier();                              \
  __builtin_amdgcn_sched_barrier(0);                         \
} while (0)

// Barrier draining VMEM stores (h visibility before flag post).
#define BAR_VM0() do {                                       \
  asm volatile("s_waitcnt vmcnt(0)" ::: "memory");           \
  __builtin_amdgcn_sched_barrier(0);                         \
  __builtin_amdgcn_s_barrier();                              \
  __builtin_amdgcn_sched_barrier(0);                         \
} while (0)

__device__ __forceinline__ float sigm_fast(float x) {
  return __builtin_amdgcn_rcpf(1.f + __expf(-x));   // abs err ~1e-6 << fp16 quant
}
__device__ __forceinline__ float tanh_fast(float x) {
  float cx = fminf(15.f, fmaxf(-15.f, x));          // clamp: no inf/inf
  float e = __expf(2.f * cx);
  return (e - 1.f) * __builtin_amdgcn_rcpf(e + 1.f);
}

// ---------------- prep kernels ----------------

// W_ih fp32 -> fp16, flat copy. 4096*1024 elems, 8 per thread.
__global__ void k_conv_wih(const float* __restrict__ w, _Float16* __restrict__ o) {
  int i = blockIdx.x * 256 + threadIdx.x;          // 0..524287
  const f4* src = (const f4*)w + (size_t)i * 2;
  f4 a = src[0], b = src[1];
  h8 r;
  r[0] = (_Float16)a[0]; r[1] = (_Float16)a[1]; r[2] = (_Float16)a[2]; r[3] = (_Float16)a[3];
  r[4] = (_Float16)b[0]; r[5] = (_Float16)b[1]; r[6] = (_Float16)b[2]; r[7] = (_Float16)b[3];
  *(h8*)(o + (size_t)i * 8) = r;
}

// W_hh fp32 [4096,1024] -> fp16 shuffled into MFMA B-fragment order:
// block b = nt*32 + kt holds lane l's 8 halves W[nt*16 + (l&15)][kt*32 + (l>>4)*8 + j]
__global__ void k_shuf_whh(const float* __restrict__ w, _Float16* __restrict__ o) {
  int cidx = blockIdx.x * 256 + threadIdx.x;       // 0..524287
  int b = cidx >> 6;                               // 0..8191 (256 nt * 32 kt)
  int lid = cidx & 63;
  int n = (b >> 5) * 16 + (lid & 15);
  int k0 = (b & 31) * 32 + (lid >> 4) * 8;
  const float* src = w + (size_t)n * HH + k0;
  h8 r;
  #pragma unroll
  for (int j = 0; j < 8; ++j) r[j] = (_Float16)src[j];
  *(h8*)(o + (size_t)b * 512 + lid * 8) = r;
}

__global__ void k_bsum(const float* __restrict__ bi, const float* __restrict__ bh,
                       float* __restrict__ o) {
  int i = blockIdx.x * 256 + threadIdx.x;          // 4096
  o[i] = bi[i] + bh[i];
}

// h0 fp32 -> fp16 into hbuf[0]; zero the flag array (ws is poisoned each launch).
__global__ void k_prep(const float* __restrict__ h0, _Float16* __restrict__ hbuf,
                       unsigned* __restrict__ bar) {
  int i = blockIdx.x * 256 + threadIdx.x;          // 65536
  hbuf[i] = (_Float16)h0[i];
  if (i < 2048) bar[i] = 0u;                       // 64 flags @ 128B stride
}

// ---------------- phase A: gates_x = x @ W_ih^T + (b_ih + b_hh) ----------------
// M=32768, N=4096, K=1024. 128x128 tile per 256-thread wg, BK=32, fp16 MFMA.
// Epilogue stores gxL in PHASE-B FRAGMENT ORDER: gxL[t][w][s][lane l][16]
// where the 16 halves per lane are (mt=0..3, r=0..3) for (m = mt*16+(l>>4)*4+r,
// col = l&15 of wg s's 16-col slice, gate w). Phase B then reads 2 coalesced
// 16B loads per lane instead of 16 scattered 2B loads.
__global__ __launch_bounds__(256) void k_gemm_gx(
    const float* __restrict__ x, const _Float16* __restrict__ wih,
    const float* __restrict__ bsum, _Float16* __restrict__ gxL) {
  __shared__ _Float16 As[128 * 40];   // pad 32->40 halves: 2-way banks only (free)
  __shared__ _Float16 Bs[128 * 40];
  const int bid = blockIdx.x;
  const int m0 = (bid >> 5) * 128;
  const int n0 = (bid & 31) * 128;
  const int tid = threadIdx.x;
  const int w = tid >> 6, l = tid & 63, q = l >> 4, lj = l & 15;
  const int wm = (w >> 1) * 64, wn = (w & 1) * 64;
  const int lrow = tid >> 1;
  const int lcol = (tid & 1) * 16;

  f4 z = {0.f, 0.f, 0.f, 0.f};
  f4 acc[4][4];
  #pragma unroll
  for (int i2 = 0; i2 < 4; ++i2)
    #pragma unroll
    for (int j2 = 0; j2 < 4; ++j2) acc[i2][j2] = z;

  for (int kt = 0; kt < 32; ++kt) {
    const int k0 = kt * 32;
    const float* xp = x + (size_t)(m0 + lrow) * HH + k0 + lcol;
    f4 a0 = ((const f4*)xp)[0];
    f4 a1 = ((const f4*)xp)[1];
    f4 a2 = ((const f4*)xp)[2];
    f4 a3 = ((const f4*)xp)[3];
    const _Float16* bp = wih + (size_t)(n0 + lrow) * HH + k0 + lcol;
    h8 b0 = ((const h8*)bp)[0];
    h8 b1 = ((const h8*)bp)[1];
    h8 lo, hi;
    lo[0] = (_Float16)a0[0]; lo[1] = (_Float16)a0[1]; lo[2] = (_Float16)a0[2]; lo[3] = (_Float16)a0[3];
    lo[4] = (_Float16)a1[0]; lo[5] = (_Float16)a1[1]; lo[6] = (_Float16)a1[2]; lo[7] = (_Float16)a1[3];
    hi[0] = (_Float16)a2[0]; hi[1] = (_Float16)a2[1]; hi[2] = (_Float16)a2[2]; hi[3] = (_Float16)a2[3];
    hi[4] = (_Float16)a3[0]; hi[5] = (_Float16)a3[1]; hi[6] = (_Float16)a3[2]; hi[7] = (_Float16)a3[3];
    __syncthreads();
    *(h8*)&As[lrow * 40 + lcol] = lo;
    *(h8*)&As[lrow * 40 + lcol + 8] = hi;
    *(h8*)&Bs[lrow * 40 + lcol] = b0;
    *(h8*)&Bs[lrow * 40 + lcol + 8] = b1;
    __syncthreads();
    h8 af[4], bf[4];
    #pragma unroll
    for (int mt = 0; mt < 4; ++mt) af[mt] = *(h8*)&As[(wm + mt * 16 + lj) * 40 + q * 8];
    #pragma unroll
    for (int nt = 0; nt < 4; ++nt) bf[nt] = *(h8*)&Bs[(wn + nt * 16 + lj) * 40 + q * 8];
    #pragma unroll
    for (int mt = 0; mt < 4; ++mt)
      #pragma unroll
      for (int nt = 0; nt < 4; ++nt)
        acc[mt][nt] = __builtin_amdgcn_mfma_f32_16x16x32_f16(af[mt], bf[nt], acc[mt][nt], 0, 0, 0);
  }
  // epilogue: add bias, store fp16 packed u64 into gxL fragment layout.
  // acc layout: col=lane&15, row=(lane>>4)*4+reg -> (mt, q, r) as used below.
  const int tt = (m0 + wm) >> 6;                   // timestep of this 64-row band
  #pragma unroll
  for (int nt = 0; nt < 4; ++nt) {
    int nbase = n0 + wn + nt * 16;                 // lj-free part of col index
    float bv = bsum[nbase + lj];
    int wq = nbase >> 10;                          // gate
    int sq = (nbase >> 4) & 63;                    // wg col-slice
    _Float16* dst = gxL + (((size_t)tt * 4 + wq) * 64 + sq) * 1024 + (q * 16 + lj) * 16;
    #pragma unroll
    for (int mt = 0; mt < 4; ++mt) {
      union { _Float16 h[4]; u64 u; } pk;
      #pragma unroll
      for (int r = 0; r < 4; ++r) pk.h[r] = (_Float16)(acc[mt][nt][r] + bv);
      *(u64*)(dst + mt * 4) = pk.u;
    }
  }
}

// ---------------- phase B: persistent reverse scan ----------------
// 64 wgs (1/CU), wg s owns h-cols [16s,16s+16); wave w computes gate-type w.
// Fence-free cross-wg h exchange via relaxed agent-scope atomics (sc1 bypass;
// L2 stays warm for wsh). Chunk barriers are RAW s_barrier + lgkmcnt(0) only:
// global loads stay in flight across them (counted waits at use), so the
// 3-deep h-chunk register lookahead actually hides the ~900cy sc1 latency.
__global__ __launch_bounds__(256, 1) void k_lstm_seq(
    const _Float16* __restrict__ gxL, const _Float16* __restrict__ wsh,
    const float* __restrict__ c0, float* __restrict__ out,
    _Float16* __restrict__ hbuf, unsigned* __restrict__ bar) {
  __shared__ _Float16 hs[2][64 * 136]; // double-buffered chunk [64 x 128], pad 8
  __shared__ float gbuf[4 * 64 * 20];  // gate exchange, row pad 16->20
  __shared__ float cs[64 * 20];        // persistent c slice
  const int tid = threadIdx.x;
  const int s = blockIdx.x;            // 0..63
  const int w = tid >> 6;
  const int l = tid & 63;
  const int q = l >> 4;
  const int lj = l & 15;
  const int em = tid >> 2;             // elementwise: row 0..63
  const int ec = (tid & 3) * 4;        // elementwise: col base (4 contiguous cols)
  const int c0r = s >> 3;              // chunk rotation: spread IF$ reads

  #pragma unroll
  for (int u = 0; u < 4; ++u) {
    int e = u * 256 + tid;             // (m = e>>4, j = e&15)
    cs[(e >> 4) * 20 + (e & 15)] = c0[(size_t)(e >> 4) * HH + s * 16 + (e & 15)];
  }

  for (int ii = 0; ii < TT; ++ii) {
    const int t = TT - 1 - ii;
    const _Float16* __restrict__ hcur = hbuf + (size_t)(ii & 1) * (BB * HH);
    _Float16* __restrict__ hnxt = hbuf + (size_t)((ii + 1) & 1) * (BB * HH);
    const unsigned tgt = (unsigned)ii; // reads need producers' flag >= ii

    // ---- gx: 2 coalesced 16B loads per lane (fragment-ordered gxL)
    const _Float16* gxb = gxL + (((size_t)t * 4 + w) * 64 + s) * 1024 + (size_t)l * 16;
    h8 g0 = *(const h8*)gxb;           // (mt=0..1, r=0..3)
    h8 g1 = *(const h8*)(gxb + 8);     // (mt=2..3, r=0..3)

    // ---- readiness: sticky per-wave mask of (flag[l] >= tgt)
    u64 rdy = 0;
    auto wait_chunk = [&](int c) {
      while (((rdy >> (c * 8)) & 0xFFull) != 0xFFull) {
        unsigned v = __hip_atomic_load(&bar[l * 32], __ATOMIC_RELAXED,
                                       __HIP_MEMORY_SCOPE_AGENT);
        rdy = __ballot(v >= tgt);
        if (((rdy >> (c * 8)) & 0xFFull) == 0xFFull) break;
        __builtin_amdgcn_s_sleep(1);
      }
    };
    auto load_chunk = [&](int c, u64* dst) {
      #pragma unroll
      for (int u = 0; u < 8; ++u) {
        int e = u * 256 + tid;         // 0..2047: row = e>>5, 8B unit (e&31)
        dst[u] = __hip_atomic_load(
            (const u64*)&hcur[(size_t)(e >> 5) * HH + c * 128 + (e & 31) * 4],
            __ATOMIC_RELAXED, __HIP_MEMORY_SCOPE_AGENT);
      }
    };

    f4 z = {0.f, 0.f, 0.f, 0.f};
    f4 acc[4];
    #pragma unroll
    for (int mt = 0; mt < 4; ++mt) acc[mt] = z;

    u64 pre[3][8];                     // 3-deep lookahead (48 VGPRs)
    wait_chunk(c0r);             load_chunk(c0r, pre[0]);
    wait_chunk((c0r + 1) & 7);   load_chunk((c0r + 1) & 7, pre[1]);
    wait_chunk((c0r + 2) & 7);   load_chunk((c0r + 2) & 7, pre[2]);

    #pragma unroll
    for (int ck = 0; ck < 8; ++ck) {
      const int ckx = (ck + c0r) & 7;
      u64* cur = pre[ck % 3];          // static after full unroll
      // stage chunk into LDS buffer ck&1; compiler inserts the counted vmcnt
      // wait for cur's loads right here (not a full drain).
      #pragma unroll
      for (int u = 0; u < 8; ++u) {
        int e = u * 256 + tid;
        *(u64*)&hs[ck & 1][(e >> 5) * 136 + (e & 31) * 4] = cur[u];
      }
      BAR_LGKM();                      // LDS-only barrier: vmem stays in flight
      if (ck < 5) {                    // refill this register buffer, 3 ahead
        int cn = (ck + 3 + c0r) & 7;
        wait_chunk(cn);
        load_chunk(cn, cur);
      }
      #pragma unroll
      for (int kk = 0; kk < 4; ++kk) {
        int blk = (w * 64 + s) * 32 + ckx * 4 + kk;
        h8 bfr = *(const h8*)&wsh[(size_t)blk * 512 + l * 8];  // L2-hot
        #pragma unroll
        for (int mt = 0; mt < 4; ++mt) {
          h8 afr = *(const h8*)&hs[ck & 1][(mt * 16 + lj) * 136 + kk * 32 + q * 8];
          acc[mt] = __builtin_amdgcn_mfma_f32_16x16x32_f16(afr, bfr, acc[mt], 0, 0, 0);
        }
      }
    }
    // add gates_x (registers), exchange via LDS
    #pragma unroll
    for (int mt = 0; mt < 4; ++mt) {
      #pragma unroll
      for (int r = 0; r < 4; ++r) {
        int m = mt * 16 + q * 4 + r;
        float gxv = (float)((mt < 2 ? g0 : g1)[(mt & 1) * 4 + r]);
        gbuf[(w * 64 + m) * 20 + lj] = acc[mt][r] + gxv;
      }
    }
    BAR_LGKM();
    // elementwise: thread handles (row em, cols ec..ec+3)
    f4 gi4 = *(f4*)&gbuf[(0 * 64 + em) * 20 + ec];
    f4 gf4 = *(f4*)&gbuf[(1 * 64 + em) * 20 + ec];
    f4 gg4 = *(f4*)&gbuf[(2 * 64 + em) * 20 + ec];
    f4 go4 = *(f4*)&gbuf[(3 * 64 + em) * 20 + ec];
    f4 cold = *(f4*)&cs[em * 20 + ec];
    f4 hn4, cn4;
    #pragma unroll
    for (int j = 0; j < 4; ++j) {
      float iv = sigm_fast(gi4[j]);
      float fv = sigm_fast(gf4[j]);
      float gv = tanh_fast(gg4[j]);
      float ov = sigm_fast(go4[j]);
      float cn = fv * cold[j] + iv * gv;
      cn4[j] = cn;
      hn4[j] = ov * tanh_fast(cn);
    }
    *(f4*)&cs[em * 20 + ec] = cn4;
    union { _Float16 h[4]; u64 u; } pk;
    #pragma unroll
    for (int j = 0; j < 4; ++j) pk.h[j] = (_Float16)hn4[j];
    __hip_atomic_store((u64*)&hnxt[(size_t)em * HH + s * 16 + ec], pk.u,
                       __ATOMIC_RELAXED, __HIP_MEMORY_SCOPE_AGENT);
    // ---- post flag ASAP: vmcnt(0) drains h stores to coherence point, then
    // barrier, then tid0 posts. out stores happen AFTER (off critical path).
    BAR_VM0();
    if (tid == 0)
      __hip_atomic_store(&bar[s * 32], (unsigned)(ii + 1), __ATOMIC_RELAXED,
                         __HIP_MEMORY_SCOPE_AGENT);
    *(f4*)&out[((size_t)t * BB + em) * HH + s * 16 + ec] = hn4;
    if (t == 0) {  // final carry (hT, cT)
      *(f4*)&out[(size_t)TT * BB * HH + (size_t)em * HH + s * 16 + ec] = hn4;
      *(f4*)&out[(size_t)TT * BB * HH + (size_t)BB * HH + (size_t)em * HH + s * 16 + ec] = cn4;
    }
  }
}

// ---------------- launch ----------------
extern "C" void kernel_launch(void* const* d_in, const int* in_sizes, int n_in,
                              void* d_out, int out_size, void* d_ws, size_t ws_size,
                              hipStream_t stream) {
  const float* x    = (const float*)d_in[0];
  const float* h0   = (const float*)d_in[1];
  const float* c0   = (const float*)d_in[2];
  const float* W_ih = (const float*)d_in[3];
  const float* W_hh = (const float*)d_in[4];
  const float* b_ih = (const float*)d_in[5];
  const float* b_hh = (const float*)d_in[6];
  float* out = (float*)d_out;

  char* ws = (char*)d_ws;
  size_t off = 0;
  auto take = [&](size_t bytes) -> void* {
    void* p = ws + off;
    off = (off + bytes + 255) & ~(size_t)255;
    return p;
  };
  _Float16* gxL   = (_Float16*)take((size_t)TT * BB * G4 * 2);  // 268 MB
  _Float16* wih_h = (_Float16*)take((size_t)G4 * HH * 2);       // 8.4 MB
  _Float16* wsh   = (_Float16*)take((size_t)G4 * HH * 2);       // 8.4 MB
  float*    bsum  = (float*)take((size_t)G4 * 4);
  _Float16* hbuf  = (_Float16*)take((size_t)2 * BB * HH * 2);   // ping-pong h
  unsigned* bar   = (unsigned*)take(64 * 32 * 4);               // 64 flags @128B
  if (off > ws_size) return;  // workspace too small -> visible validation failure

  k_conv_wih<<<2048, 256, 0, stream>>>(W_ih, wih_h);
  k_shuf_whh<<<2048, 256, 0, stream>>>(W_hh, wsh);
  k_bsum<<<16, 256, 0, stream>>>(b_ih, b_hh, bsum);
  k_prep<<<256, 256, 0, stream>>>(h0, hbuf, bar);
  k_gemm_gx<<<8192, 256, 0, stream>>>(x, wih_h, bsum, gxL);
  k_lstm_seq<<<64, 256, 0, stream>>>(gxL, wsh, c0, out, hbuf, bar);
}

// Round 4
// 3986.745 us; speedup vs baseline: 1.2273x; 1.2273x over previous
//
#include <hip/hip_runtime.h>

#define TT 512
#define BB 64
#define HH 1024
#define G4 4096

typedef _Float16 h8 __attribute__((ext_vector_type(8)));
typedef float f4 __attribute__((ext_vector_type(4)));
typedef unsigned long long u64;

// Minimal chunk barrier: drain LDS ops, sync. NO vmcnt, NO sched_barrier —
// global loads stay in flight across it; the compiler inserts counted vmcnt
// waits at the register uses (ds_write of prefetched h). "memory" keeps LDS
// reads/writes from crossing.
#define BARX() asm volatile("s_waitcnt lgkmcnt(0)\ns_barrier" ::: "memory")

__device__ __forceinline__ float sigm_fast(float x) {
  return __builtin_amdgcn_rcpf(1.f + __expf(-x));   // abs err ~1e-6 << fp16 quant
}
__device__ __forceinline__ float tanh_fast(float x) {
  float cx = fminf(15.f, fmaxf(-15.f, x));          // clamp: no inf/inf
  float e = __expf(2.f * cx);
  return (e - 1.f) * __builtin_amdgcn_rcpf(e + 1.f);
}

// ---------------- prep kernels ----------------

// W_ih fp32 -> fp16, flat copy. 4096*1024 elems, 8 per thread.
__global__ void k_conv_wih(const float* __restrict__ w, _Float16* __restrict__ o) {
  int i = blockIdx.x * 256 + threadIdx.x;          // 0..524287
  const f4* src = (const f4*)w + (size_t)i * 2;
  f4 a = src[0], b = src[1];
  h8 r;
  r[0] = (_Float16)a[0]; r[1] = (_Float16)a[1]; r[2] = (_Float16)a[2]; r[3] = (_Float16)a[3];
  r[4] = (_Float16)b[0]; r[5] = (_Float16)b[1]; r[6] = (_Float16)b[2]; r[7] = (_Float16)b[3];
  *(h8*)(o + (size_t)i * 8) = r;
}

// W_hh fp32 [4096,1024] -> fp16 shuffled into MFMA B-fragment order:
// block b = nt*32 + kt holds lane l's 8 halves W[nt*16 + (l&15)][kt*32 + (l>>4)*8 + j]
__global__ void k_shuf_whh(const float* __restrict__ w, _Float16* __restrict__ o) {
  int cidx = blockIdx.x * 256 + threadIdx.x;       // 0..524287
  int b = cidx >> 6;                               // 0..8191 (256 nt * 32 kt)
  int lid = cidx & 63;
  int n = (b >> 5) * 16 + (lid & 15);
  int k0 = (b & 31) * 32 + (lid >> 4) * 8;
  const float* src = w + (size_t)n * HH + k0;
  h8 r;
  #pragma unroll
  for (int j = 0; j < 8; ++j) r[j] = (_Float16)src[j];
  *(h8*)(o + (size_t)b * 512 + lid * 8) = r;
}

__global__ void k_bsum(const float* __restrict__ bi, const float* __restrict__ bh,
                       float* __restrict__ o) {
  int i = blockIdx.x * 256 + threadIdx.x;          // 4096
  o[i] = bi[i] + bh[i];
}

// h0 fp32 -> fp16 into hbuf[0]; zero the flag array (ws is poisoned each launch).
__global__ void k_prep(const float* __restrict__ h0, _Float16* __restrict__ hbuf,
                       unsigned* __restrict__ bar) {
  int i = blockIdx.x * 256 + threadIdx.x;          // 65536
  hbuf[i] = (_Float16)h0[i];
  if (i < 2048) bar[i] = 0u;                       // 64 flags @ 128B stride
}

// ---------------- phase A: gates_x = x @ W_ih^T + (b_ih + b_hh) ----------------
// M=32768, N=4096, K=1024. 128x128 tile per 256-thread wg, BK=32, fp16 MFMA.
// Epilogue stores gxL in PHASE-B FRAGMENT ORDER: gxL[t][w][s][lane l][16].
__global__ __launch_bounds__(256) void k_gemm_gx(
    const float* __restrict__ x, const _Float16* __restrict__ wih,
    const float* __restrict__ bsum, _Float16* __restrict__ gxL) {
  __shared__ _Float16 As[128 * 40];   // pad 32->40 halves: 2-way banks only (free)
  __shared__ _Float16 Bs[128 * 40];
  const int bid = blockIdx.x;
  const int m0 = (bid >> 5) * 128;
  const int n0 = (bid & 31) * 128;
  const int tid = threadIdx.x;
  const int w = tid >> 6, l = tid & 63, q = l >> 4, lj = l & 15;
  const int wm = (w >> 1) * 64, wn = (w & 1) * 64;
  const int lrow = tid >> 1;
  const int lcol = (tid & 1) * 16;

  f4 z = {0.f, 0.f, 0.f, 0.f};
  f4 acc[4][4];
  #pragma unroll
  for (int i2 = 0; i2 < 4; ++i2)
    #pragma unroll
    for (int j2 = 0; j2 < 4; ++j2) acc[i2][j2] = z;

  for (int kt = 0; kt < 32; ++kt) {
    const int k0 = kt * 32;
    const float* xp = x + (size_t)(m0 + lrow) * HH + k0 + lcol;
    f4 a0 = ((const f4*)xp)[0];
    f4 a1 = ((const f4*)xp)[1];
    f4 a2 = ((const f4*)xp)[2];
    f4 a3 = ((const f4*)xp)[3];
    const _Float16* bp = wih + (size_t)(n0 + lrow) * HH + k0 + lcol;
    h8 b0 = ((const h8*)bp)[0];
    h8 b1 = ((const h8*)bp)[1];
    h8 lo, hi;
    lo[0] = (_Float16)a0[0]; lo[1] = (_Float16)a0[1]; lo[2] = (_Float16)a0[2]; lo[3] = (_Float16)a0[3];
    lo[4] = (_Float16)a1[0]; lo[5] = (_Float16)a1[1]; lo[6] = (_Float16)a1[2]; lo[7] = (_Float16)a1[3];
    hi[0] = (_Float16)a2[0]; hi[1] = (_Float16)a2[1]; hi[2] = (_Float16)a2[2]; hi[3] = (_Float16)a2[3];
    hi[4] = (_Float16)a3[0]; hi[5] = (_Float16)a3[1]; hi[6] = (_Float16)a3[2]; hi[7] = (_Float16)a3[3];
    __syncthreads();
    *(h8*)&As[lrow * 40 + lcol] = lo;
    *(h8*)&As[lrow * 40 + lcol + 8] = hi;
    *(h8*)&Bs[lrow * 40 + lcol] = b0;
    *(h8*)&Bs[lrow * 40 + lcol + 8] = b1;
    __syncthreads();
    h8 af[4], bf[4];
    #pragma unroll
    for (int mt = 0; mt < 4; ++mt) af[mt] = *(h8*)&As[(wm + mt * 16 + lj) * 40 + q * 8];
    #pragma unroll
    for (int nt = 0; nt < 4; ++nt) bf[nt] = *(h8*)&Bs[(wn + nt * 16 + lj) * 40 + q * 8];
    #pragma unroll
    for (int mt = 0; mt < 4; ++mt)
      #pragma unroll
      for (int nt = 0; nt < 4; ++nt)
        acc[mt][nt] = __builtin_amdgcn_mfma_f32_16x16x32_f16(af[mt], bf[nt], acc[mt][nt], 0, 0, 0);
  }
  // epilogue: add bias, store fp16 packed u64 into gxL fragment layout.
  const int tt = (m0 + wm) >> 6;                   // timestep of this 64-row band
  #pragma unroll
  for (int nt = 0; nt < 4; ++nt) {
    int nbase = n0 + wn + nt * 16;                 // lj-free part of col index
    float bv = bsum[nbase + lj];
    int wq = nbase >> 10;                          // gate
    int sq = (nbase >> 4) & 63;                    // wg col-slice
    _Float16* dst = gxL + (((size_t)tt * 4 + wq) * 64 + sq) * 1024 + (q * 16 + lj) * 16;
    #pragma unroll
    for (int mt = 0; mt < 4; ++mt) {
      union { _Float16 h[4]; u64 u; } pk;
      #pragma unroll
      for (int r = 0; r < 4; ++r) pk.h[r] = (_Float16)(acc[mt][nt][r] + bv);
      *(u64*)(dst + mt * 4) = pk.u;
    }
  }
}

// ---------------- phase B: persistent reverse scan ----------------
// 64 wgs (1/CU), wg s owns h-cols [16s,16s+16); wave w computes gate-type w.
// Fence-free cross-wg h exchange via relaxed agent-scope atomics.
// ONE flag gather per step (at END of previous step, after own post) — no
// polls on the GEMM critical path, so prefetched loads are never drained by
// a poll's implicit in-order vmcnt wait. Chunk barriers are lgkm-only.
__global__ __launch_bounds__(256, 1) void k_lstm_seq(
    const _Float16* __restrict__ gxL, const _Float16* __restrict__ wsh,
    const float* __restrict__ c0, float* __restrict__ out,
    _Float16* __restrict__ hbuf, unsigned* __restrict__ bar) {
  __shared__ _Float16 hs[2][64 * 136]; // double-buffered chunk [64 x 128], pad 8
  __shared__ float gbuf[4 * 64 * 20];  // gate exchange, row pad 16->20
  __shared__ float cs[64 * 20];        // persistent c slice
  const int tid = threadIdx.x;
  const int s = blockIdx.x;            // 0..63
  const int w = tid >> 6;
  const int l = tid & 63;
  const int q = l >> 4;
  const int lj = l & 15;
  const int em = tid >> 2;             // elementwise: row 0..63
  const int ec = (tid & 3) * 4;        // elementwise: col base

  #pragma unroll
  for (int u = 0; u < 4; ++u) {
    int e = u * 256 + tid;             // (m = e>>4, j = e&15)
    cs[(e >> 4) * 20 + (e & 15)] = c0[(size_t)(e >> 4) * HH + s * 16 + (e & 15)];
  }
  // No initial flag wait: step 0 needs flags >= 0, trivially true (k_prep).

  for (int ii = 0; ii < TT; ++ii) {
    const int t = TT - 1 - ii;
    const _Float16* __restrict__ hcur = hbuf + (size_t)(ii & 1) * (BB * HH);
    _Float16* __restrict__ hnxt = hbuf + (size_t)((ii + 1) & 1) * (BB * HH);

    // ---- gx: 2 coalesced 16B loads (fragment-ordered gxL); consumed late.
    const _Float16* gxb = gxL + (((size_t)t * 4 + w) * 64 + s) * 1024 + (size_t)l * 16;
    h8 g0 = *(const h8*)gxb;
    h8 g1 = *(const h8*)(gxb + 8);

    // ---- prefetch h chunks 0,1 into regs + wsh chunk 0 fragments.
    // Readiness was established by the gather at the end of the previous step.
    u64 preA[8], preB[8];
    #pragma unroll
    for (int u = 0; u < 8; ++u) {
      int e = u * 256 + tid;           // row = e>>5, 8B unit (e&31)
      preA[u] = __hip_atomic_load(
          (const u64*)&hcur[(size_t)(e >> 5) * HH + 0 * 128 + (e & 31) * 4],
          __ATOMIC_RELAXED, __HIP_MEMORY_SCOPE_AGENT);
    }
    #pragma unroll
    for (int u = 0; u < 8; ++u) {
      int e = u * 256 + tid;
      preB[u] = __hip_atomic_load(
          (const u64*)&hcur[(size_t)(e >> 5) * HH + 1 * 128 + (e & 31) * 4],
          __ATOMIC_RELAXED, __HIP_MEMORY_SCOPE_AGENT);
    }
    h8 bcur[4];
    #pragma unroll
    for (int kk = 0; kk < 4; ++kk)
      bcur[kk] = *(const h8*)&wsh[(size_t)((w * 64 + s) * 32 + kk) * 512 + l * 8];

    f4 z = {0.f, 0.f, 0.f, 0.f};
    f4 acc[4];
    #pragma unroll
    for (int mt = 0; mt < 4; ++mt) acc[mt] = z;

    #pragma unroll
    for (int ck = 0; ck < 8; ++ck) {
      u64* cur = (ck & 1) ? preB : preA;
      // stage chunk ck into LDS buffer ck&1; compiler emits a COUNTED vmcnt
      // wait here for cur's loads (issued 2 chunks ago: ~800cy cover).
      #pragma unroll
      for (int u = 0; u < 8; ++u) {
        int e = u * 256 + tid;
        *(u64*)&hs[ck & 1][(e >> 5) * 136 + (e & 31) * 4] = cur[u];
      }
      // prefetch next chunk's wsh fragments BEFORE the barrier: L2 latency
      // hides under barrier-sync + this chunk's MFMAs.
      h8 bnext[4];
      if (ck < 7) {
        #pragma unroll
        for (int kk = 0; kk < 4; ++kk)
          bnext[kk] = *(const h8*)&wsh[(size_t)((w * 64 + s) * 32 + (ck + 1) * 4 + kk) * 512 + l * 8];
      }
      BARX();                          // lgkm-only: vmem stays in flight
      // refill this register buffer 2 chunks ahead (in flight across 2 BARX)
      if (ck < 6) {
        #pragma unroll
        for (int u = 0; u < 8; ++u) {
          int e = u * 256 + tid;
          cur[u] = __hip_atomic_load(
              (const u64*)&hcur[(size_t)(e >> 5) * HH + (ck + 2) * 128 + (e & 31) * 4],
              __ATOMIC_RELAXED, __HIP_MEMORY_SCOPE_AGENT);
        }
      }
      #pragma unroll
      for (int kk = 0; kk < 4; ++kk) {
        #pragma unroll
        for (int mt = 0; mt < 4; ++mt) {
          h8 afr = *(h8*)&hs[ck & 1][(mt * 16 + lj) * 136 + kk * 32 + q * 8];
          acc[mt] = __builtin_amdgcn_mfma_f32_16x16x32_f16(afr, bcur[kk], acc[mt], 0, 0, 0);
        }
      }
      if (ck < 7) {
        #pragma unroll
        for (int kk = 0; kk < 4; ++kk) bcur[kk] = bnext[kk];
      }
    }
    // add gates_x (registers), exchange via LDS
    #pragma unroll
    for (int mt = 0; mt < 4; ++mt) {
      #pragma unroll
      for (int r = 0; r < 4; ++r) {
        int m = mt * 16 + q * 4 + r;
        float gxv = (float)((mt < 2 ? g0 : g1)[(mt & 1) * 4 + r]);
        gbuf[(w * 64 + m) * 20 + lj] = acc[mt][r] + gxv;
      }
    }
    __syncthreads();
    // elementwise: thread handles (row em, cols ec..ec+3)
    f4 gi4 = *(f4*)&gbuf[(0 * 64 + em) * 20 + ec];
    f4 gf4 = *(f4*)&gbuf[(1 * 64 + em) * 20 + ec];
    f4 gg4 = *(f4*)&gbuf[(2 * 64 + em) * 20 + ec];
    f4 go4 = *(f4*)&gbuf[(3 * 64 + em) * 20 + ec];
    f4 cold = *(f4*)&cs[em * 20 + ec];
    f4 hn4, cn4;
    #pragma unroll
    for (int j = 0; j < 4; ++j) {
      float iv = sigm_fast(gi4[j]);
      float fv = sigm_fast(gf4[j]);
      float gv = tanh_fast(gg4[j]);
      float ov = sigm_fast(go4[j]);
      float cn = fv * cold[j] + iv * gv;
      cn4[j] = cn;
      hn4[j] = ov * tanh_fast(cn);
    }
    *(f4*)&cs[em * 20 + ec] = cn4;
    union { _Float16 h[4]; u64 u; } pk;
    #pragma unroll
    for (int j = 0; j < 4; ++j) pk.h[j] = (_Float16)hn4[j];
    __hip_atomic_store((u64*)&hnxt[(size_t)em * HH + s * 16 + ec], pk.u,
                       __ATOMIC_RELAXED, __HIP_MEMORY_SCOPE_AGENT);
    // ---- __syncthreads drains vmcnt(0): h stores at coherence point; post.
    __syncthreads();
    if (tid == 0)
      __hip_atomic_store(&bar[s * 32], (unsigned)(ii + 1), __ATOMIC_RELAXED,
                         __HIP_MEMORY_SCOPE_AGENT);
    // ---- ONE flag gather per step, overlapping stragglers with step tail.
    // Guards next step's h reads; also guarantees no producer can overwrite
    // hcur' before every wg has passed this point with flags >= ii+1.
    if (ii + 1 < TT) {
      const unsigned tgt = (unsigned)(ii + 1);
      while (true) {
        unsigned v = __hip_atomic_load(&bar[l * 32], __ATOMIC_RELAXED,
                                       __HIP_MEMORY_SCOPE_AGENT);
        if (__all(v >= tgt)) break;
        __builtin_amdgcn_s_sleep(1);
      }
    }
    // out stores: fire-and-forget, off the critical path.
    *(f4*)&out[((size_t)t * BB + em) * HH + s * 16 + ec] = hn4;
    if (t == 0) {  // final carry (hT, cT)
      *(f4*)&out[(size_t)TT * BB * HH + (size_t)em * HH + s * 16 + ec] = hn4;
      *(f4*)&out[(size_t)TT * BB * HH + (size_t)BB * HH + (size_t)em * HH + s * 16 + ec] = cn4;
    }
  }
}

// ---------------- launch ----------------
extern "C" void kernel_launch(void* const* d_in, const int* in_sizes, int n_in,
                              void* d_out, int out_size, void* d_ws, size_t ws_size,
                              hipStream_t stream) {
  const float* x    = (const float*)d_in[0];
  const float* h0   = (const float*)d_in[1];
  const float* c0   = (const float*)d_in[2];
  const float* W_ih = (const float*)d_in[3];
  const float* W_hh = (const float*)d_in[4];
  const float* b_ih = (const float*)d_in[5];
  const float* b_hh = (const float*)d_in[6];
  float* out = (float*)d_out;

  char* ws = (char*)d_ws;
  size_t off = 0;
  auto take = [&](size_t bytes) -> void* {
    void* p = ws + off;
    off = (off + bytes + 255) & ~(size_t)255;
    return p;
  };
  _Float16* gxL   = (_Float16*)take((size_t)TT * BB * G4 * 2);  // 268 MB
  _Float16* wih_h = (_Float16*)take((size_t)G4 * HH * 2);       // 8.4 MB
  _Float16* wsh   = (_Float16*)take((size_t)G4 * HH * 2);       // 8.4 MB
  float*    bsum  = (float*)take((size_t)G4 * 4);
  _Float16* hbuf  = (_Float16*)take((size_t)2 * BB * HH * 2);   // ping-pong h
  unsigned* bar   = (unsigned*)take(64 * 32 * 4);               // 64 flags @128B
  if (off > ws_size) return;  // workspace too small -> visible validation failure

  k_conv_wih<<<2048, 256, 0, stream>>>(W_ih, wih_h);
  k_shuf_whh<<<2048, 256, 0, stream>>>(W_hh, wsh);
  k_bsum<<<16, 256, 0, stream>>>(b_ih, b_hh, bsum);
  k_prep<<<256, 256, 0, stream>>>(h0, hbuf, bar);
  k_gemm_gx<<<8192, 256, 0, stream>>>(x, wih_h, bsum, gxL);
  k_lstm_seq<<<64, 256, 0, stream>>>(gxL, wsh, c0, out, hbuf, bar);
}